// Round 6
// baseline (270.665 us; speedup 1.0000x reference)
//
#include <hip/hip_runtime.h>

// DilatedReparamBlock folded into one 13x13 depthwise conv + bias.
//
// R9 = R8 + forced register allocation. R8 post-mortem: the {7,6} ky-split
// needs ~180 VGPR, but __launch_bounds__(64,2) only sets a LOWER bound on
// waves/EU; the compiler targeted 4 waves/EU (128-VGPR cap) and spilled the
// weight arrays to scratch (+280 MB/dispatch HBM traffic, VALUBusy 36%).
// Occupancy is LDS-capped at 2 waves/EU anyway, so we pin it:
//   __attribute__((amdgpu_waves_per_eu(2,2))) -> VGPR budget 256, no spill.
// Everything else identical to R8:
//  - ky split {0..6}, {7..12}: 13 + 12 input-row passes = 125 b128 window
//    reads/lane (conflict-per-read model confirmed R3/R7/R8: ~26 cyc/read
//    intrinsic, count is the only lever);
//  - group weights (7x13 / 6x13) in VGPRs via broadcast LDS reads;
//  - 64 thr, 7x8-col tiles, PW=68, register prefetch of the plane.

#define CCH 384
#define SP 56
#define PW 68              // 56 + 2*6 padding
#define NPLANES (16*384)

__global__ __launch_bounds__(64)
__attribute__((amdgpu_waves_per_eu(2, 2)))
void drb_conv13_r9(
    const float* __restrict__ x,
    const float* __restrict__ w_lk, const float* __restrict__ w_b0,
    const float* __restrict__ w_b1, const float* __restrict__ w_b2,
    const float* __restrict__ w_b3, const float* __restrict__ w_b4,
    const float* __restrict__ w_b5,
    const float* __restrict__ gamma, const float* __restrict__ beta,
    const float* __restrict__ mean, const float* __restrict__ var,
    float* __restrict__ out)
{
    __shared__ __align__(16) float sx[PW * PW];   // 18496 B padded plane
    __shared__ __align__(16) float sw[13 * 16];   // merged weights, rows padded to 16

    const int plane = blockIdx.x;                 // n*384 + c
    const int c = plane % CCH;
    const int tid = threadIdx.x;
    const float* __restrict__ xp = x + (size_t)plane * (SP * SP);

    // --- prefetch plane into registers (HBM latency hides under LDS init) ---
    float4 stage[13];
    #pragma unroll
    for (int k = 0; k < 13; k++) {
        int i4 = tid + 64 * k;
        if (i4 < SP * SP / 4) stage[k] = ((const float4*)xp)[i4];
    }

    // --- BN fold constants (wave-uniform -> scalar loads) ---
    float S[7];
    float bias = 0.f;
    #pragma unroll
    for (int j = 0; j < 7; j++) {
        float inv = gamma[j * CCH + c] * rsqrtf(var[j * CCH + c] + 1e-5f);
        S[j] = inv;
        bias += beta[j * CCH + c] - mean[j * CCH + c] * inv;
    }

    // --- zero padded tile (b128 stores); single wave -> ops stay ordered ---
    {
        float4 z = make_float4(0.f, 0.f, 0.f, 0.f);
        #pragma unroll
        for (int k = 0; k < 19; k++) {
            int i = tid + 64 * k;
            if (i < PW * PW / 4) ((float4*)sx)[i] = z;
        }
    }

    // --- build merged 13x13 weights (208 slots incl. row pad) ---
    #pragma unroll
    for (int k = 0; k < 4; k++) {
        int t = tid + 64 * k;
        if (t < 13 * 16) {
            int ky = t >> 4, kx = t & 15;
            float w = 0.f;
            if (kx < 13) {
                w = S[0] * w_lk[c * 169 + ky * 13 + kx];                   // 13x13 d1
                if (ky >= 4 && ky <= 8 && kx >= 4 && kx <= 8)              // 5x5 d1 @4
                    w += S[1] * w_b0[c * 25 + (ky - 4) * 5 + (kx - 4)];
                if (ky >= 3 && ky <= 9 && kx >= 3 && kx <= 9)              // 7x7 d1 @3
                    w += S[2] * w_b1[c * 49 + (ky - 3) * 7 + (kx - 3)];
                if (!(ky & 1) && !(kx & 1))                                // 7x7 d2
                    w += S[3] * w_b2[c * 49 + (ky >> 1) * 7 + (kx >> 1)];
                if (ky >= 3 && ky <= 9 && (ky - 3) % 3 == 0 &&
                    kx >= 3 && kx <= 9 && (kx - 3) % 3 == 0)               // 3x3 d3
                    w += S[4] * w_b3[c * 9 + ((ky - 3) / 3) * 3 + (kx - 3) / 3];
                if (ky >= 2 && ky <= 10 && (ky - 2) % 4 == 0 &&
                    kx >= 2 && kx <= 10 && (kx - 2) % 4 == 0)              // 3x3 d4
                    w += S[5] * w_b4[c * 9 + ((ky - 2) / 4) * 3 + (kx - 2) / 4];
                if (ky >= 1 && ky <= 11 && (ky - 1) % 5 == 0 &&
                    kx >= 1 && kx <= 11 && (kx - 1) % 5 == 0)              // 3x3 d5
                    w += S[6] * w_b5[c * 9 + ((ky - 1) / 5) * 3 + (kx - 1) / 5];
            }
            sw[t] = w;
        }
    }

    // --- write staged plane into LDS (after zero; same-wave LDS ops ordered) ---
    #pragma unroll
    for (int k = 0; k < 13; k++) {
        int i4 = tid + 64 * k;
        if (i4 < SP * SP / 4) {
            int r = i4 / 14;                 // 14 float4 per 56-wide row
            int col = (i4 - r * 14) * 4;
            float* d = &sx[(r + 6) * PW + col + 6];   // word-even -> 8B aligned
            ((float2*)d)[0] = make_float2(stage[k].x, stage[k].y);
            ((float2*)d)[1] = make_float2(stage[k].z, stage[k].w);
        }
    }
    __syncthreads();

    // --- compute: lane (xg,yg) -> out rows [7yg..7yg+6], cols [8xg..8xg+7] ---
    const int xg = tid & 7;
    const int yg = tid >> 3;
    const int xgc = (xg < 7) ? xg : 3;       // idle lane: same-address broadcast with xg=3
    const int Yb = yg * 7;
    const float* __restrict__ sbase = &sx[Yb * PW + 8 * xgc];

    float acc[7][8];
    #pragma unroll
    for (int r = 0; r < 7; r++)
        #pragma unroll
        for (int j = 0; j < 8; j++) acc[r][j] = 0.f;

    // ===== group A: ky 0..6, input rows i = 0..12 (13 reads) =====
    {
        float wA[7][13];   // wave-uniform -> broadcast LDS reads into VGPRs
        #pragma unroll
        for (int dy = 0; dy < 7; dy++) {
            const float* wr = &sw[dy * 16];
            #pragma unroll
            for (int q = 0; q < 3; q++) {
                float4 t = ((const float4*)wr)[q];
                wA[dy][4*q+0] = t.x; wA[dy][4*q+1] = t.y;
                wA[dy][4*q+2] = t.z; wA[dy][4*q+3] = t.w;
            }
            wA[dy][12] = wr[12];
        }
        #pragma unroll
        for (int i = 0; i < 13; i++) {
            float4 win4[5];
            #pragma unroll
            for (int q = 0; q < 5; q++)
                win4[q] = *(const float4*)(sbase + i * PW + 4 * q);
            const float* win = (const float*)win4;
            #pragma unroll
            for (int dy = 0; dy < 7; dy++) {
                const int r = i - dy;
                if (r >= 0 && r < 7) {
                    #pragma unroll
                    for (int kx = 0; kx < 13; kx++) {
                        const float wv = wA[dy][kx];
                        #pragma unroll
                        for (int j = 0; j < 8; j++)
                            acc[r][j] = fmaf(wv, win[kx + j], acc[r][j]);
                    }
                }
            }
        }
    }

    // ===== group B: ky 7..12, input rows i = 7..18 (12 reads) =====
    {
        float wB[6][13];
        #pragma unroll
        for (int dy = 0; dy < 6; dy++) {
            const float* wr = &sw[(7 + dy) * 16];
            #pragma unroll
            for (int q = 0; q < 3; q++) {
                float4 t = ((const float4*)wr)[q];
                wB[dy][4*q+0] = t.x; wB[dy][4*q+1] = t.y;
                wB[dy][4*q+2] = t.z; wB[dy][4*q+3] = t.w;
            }
            wB[dy][12] = wr[12];
        }
        #pragma unroll
        for (int i = 7; i < 19; i++) {
            float4 win4[5];
            #pragma unroll
            for (int q = 0; q < 5; q++)
                win4[q] = *(const float4*)(sbase + i * PW + 4 * q);
            const float* win = (const float*)win4;
            #pragma unroll
            for (int dy = 0; dy < 6; dy++) {
                const int r = i - 7 - dy;    // ky = 7+dy
                if (r >= 0 && r < 7) {
                    #pragma unroll
                    for (int kx = 0; kx < 13; kx++) {
                        const float wv = wB[dy][kx];
                        #pragma unroll
                        for (int j = 0; j < 8; j++)
                            acc[r][j] = fmaf(wv, win[kx + j], acc[r][j]);
                    }
                }
            }
        }
    }

    // --- epilogue: +bias, 2x float4 stores per row, idle col group masked ---
    if (xg < 7) {
        float* op = out + (size_t)plane * (SP * SP) + Yb * SP + 8 * xg;
        #pragma unroll
        for (int r = 0; r < 7; r++) {
            float4 v0 = make_float4(acc[r][0] + bias, acc[r][1] + bias,
                                    acc[r][2] + bias, acc[r][3] + bias);
            float4 v1 = make_float4(acc[r][4] + bias, acc[r][5] + bias,
                                    acc[r][6] + bias, acc[r][7] + bias);
            *(float4*)(op + r * SP) = v0;
            *(float4*)(op + r * SP + 4) = v1;
        }
    }
}

extern "C" void kernel_launch(void* const* d_in, const int* in_sizes, int n_in,
                              void* d_out, int out_size, void* d_ws, size_t ws_size,
                              hipStream_t stream) {
    const float* x    = (const float*)d_in[0];
    const float* w_lk = (const float*)d_in[1];
    const float* w_b0 = (const float*)d_in[2];
    const float* w_b1 = (const float*)d_in[3];
    const float* w_b2 = (const float*)d_in[4];
    const float* w_b3 = (const float*)d_in[5];
    const float* w_b4 = (const float*)d_in[6];
    const float* w_b5 = (const float*)d_in[7];
    const float* bn_g = (const float*)d_in[8];
    const float* bn_b = (const float*)d_in[9];
    const float* bn_m = (const float*)d_in[10];
    const float* bn_v = (const float*)d_in[11];
    float* out = (float*)d_out;

    drb_conv13_r9<<<dim3(NPLANES), dim3(64), 0, stream>>>(
        x, w_lk, w_b0, w_b1, w_b2, w_b3, w_b4, w_b5,
        bn_g, bn_b, bn_m, bn_v, out);
}

// Round 8
// 269.447 us; speedup vs baseline: 1.0045x; 1.0045x over previous
//
#include <hip/hip_runtime.h>

// DilatedReparamBlock folded into one 13x13 depthwise conv + bias.
//
// R11 = R10 resubmitted (container infra failed twice; no kernel data).
// R10: {7,6} ky-split WITHOUT spills, fitted to the hard 128-VGPR cap.
// R8/R9 post-mortem: compiler clamps VGPR at 128 (waves_per_eu attr ignored)
// and spilled the 91-float weight group to scratch (+280 MB/dispatch HBM).
// Fix: hybrid weight storage per group — 5 rows (65 floats) in SGPRs via
// readfirstlane (R7 proved 52 SGPR floats work; SGPR file is idle during
// compute) + 2 rows (26 floats) in VGPRs. Peak VGPR demand ~112.
//  - reads: 13 + 12 input-row passes = 125 b128 window reads/lane
//    (R7: 185; conflict-per-read ~26 cyc is intrinsic, count is the lever);
//  - halo-only LDS zero (~7 writes/lane vs 19): interior is fully
//    overwritten by staging, only pad ring needs zeroing;
//  - else R7: 64 thr, 7x8-col lane tiles, PW=68, register plane prefetch.

#define CCH 384
#define SP 56
#define PW 68              // 56 + 2*6 padding
#define NPLANES (16*384)

__device__ __forceinline__ float rfl(float v) {
    return __int_as_float(__builtin_amdgcn_readfirstlane(__float_as_int(v)));
}

__global__ __launch_bounds__(64) void drb_conv13_r11(
    const float* __restrict__ x,
    const float* __restrict__ w_lk, const float* __restrict__ w_b0,
    const float* __restrict__ w_b1, const float* __restrict__ w_b2,
    const float* __restrict__ w_b3, const float* __restrict__ w_b4,
    const float* __restrict__ w_b5,
    const float* __restrict__ gamma, const float* __restrict__ beta,
    const float* __restrict__ mean, const float* __restrict__ var,
    float* __restrict__ out)
{
    __shared__ __align__(16) float sx[PW * PW];   // 18496 B padded plane
    __shared__ __align__(16) float sw[13 * 16];   // merged weights, rows padded to 16

    const int plane = blockIdx.x;                 // n*384 + c
    const int c = plane % CCH;
    const int tid = threadIdx.x;
    const float* __restrict__ xp = x + (size_t)plane * (SP * SP);

    // --- prefetch plane into registers (HBM latency hides under LDS init) ---
    float4 stage[13];
    #pragma unroll
    for (int k = 0; k < 13; k++) {
        int i4 = tid + 64 * k;
        if (i4 < SP * SP / 4) stage[k] = ((const float4*)xp)[i4];
    }

    // --- BN fold constants (wave-uniform -> scalar loads) ---
    float S[7];
    float bias = 0.f;
    #pragma unroll
    for (int j = 0; j < 7; j++) {
        float inv = gamma[j * CCH + c] * rsqrtf(var[j * CCH + c] + 1e-5f);
        S[j] = inv;
        bias += beta[j * CCH + c] - mean[j * CCH + c] * inv;
    }

    // --- halo-only zero: pad ring; interior rows 6..61 words 6..61 are
    //     fully covered by the staging writes below ---
    {
        float4 z4 = make_float4(0.f, 0.f, 0.f, 0.f);
        float2 z2 = make_float2(0.f, 0.f);
        // top rows 0..5 and bottom rows 62..67, full width: 12 rows x 17 b128
        #pragma unroll
        for (int k = 0; k < 4; k++) {
            int task = tid + 64 * k;
            if (task < 204) {
                int rr = task / 17;            // 0..11
                int c4 = task - rr * 17;       // 0..16
                int row = (rr < 6) ? rr : (rr + 56);   // 0..5, 62..67
                ((float4*)&sx[row * PW])[c4] = z4;
            }
        }
        // side pads of rows 6..61: words 0..5 and 62..67
        if (tid < 56) {
            float* rp = &sx[(6 + tid) * PW];
            *(float4*)(rp) = z4;           // words 0..3
            *(float2*)(rp + 4) = z2;       // words 4..5
            *(float2*)(rp + 62) = z2;      // words 62..63
            *(float4*)(rp + 64) = z4;      // words 64..67
        }
    }

    // --- build merged 13x13 weights (208 slots incl. row pad) ---
    #pragma unroll
    for (int k = 0; k < 4; k++) {
        int t = tid + 64 * k;
        if (t < 13 * 16) {
            int ky = t >> 4, kx = t & 15;
            float w = 0.f;
            if (kx < 13) {
                w = S[0] * w_lk[c * 169 + ky * 13 + kx];                   // 13x13 d1
                if (ky >= 4 && ky <= 8 && kx >= 4 && kx <= 8)              // 5x5 d1 @4
                    w += S[1] * w_b0[c * 25 + (ky - 4) * 5 + (kx - 4)];
                if (ky >= 3 && ky <= 9 && kx >= 3 && kx <= 9)              // 7x7 d1 @3
                    w += S[2] * w_b1[c * 49 + (ky - 3) * 7 + (kx - 3)];
                if (!(ky & 1) && !(kx & 1))                                // 7x7 d2
                    w += S[3] * w_b2[c * 49 + (ky >> 1) * 7 + (kx >> 1)];
                if (ky >= 3 && ky <= 9 && (ky - 3) % 3 == 0 &&
                    kx >= 3 && kx <= 9 && (kx - 3) % 3 == 0)               // 3x3 d3
                    w += S[4] * w_b3[c * 9 + ((ky - 3) / 3) * 3 + (kx - 3) / 3];
                if (ky >= 2 && ky <= 10 && (ky - 2) % 4 == 0 &&
                    kx >= 2 && kx <= 10 && (kx - 2) % 4 == 0)              // 3x3 d4
                    w += S[5] * w_b4[c * 9 + ((ky - 2) / 4) * 3 + (kx - 2) / 4];
                if (ky >= 1 && ky <= 11 && (ky - 1) % 5 == 0 &&
                    kx >= 1 && kx <= 11 && (kx - 1) % 5 == 0)              // 3x3 d5
                    w += S[6] * w_b5[c * 9 + ((ky - 1) / 5) * 3 + (kx - 1) / 5];
            }
            sw[t] = w;
        }
    }

    // --- write staged plane into LDS (rows 6..61, words 6..61) ---
    #pragma unroll
    for (int k = 0; k < 13; k++) {
        int i4 = tid + 64 * k;
        if (i4 < SP * SP / 4) {
            int r = i4 / 14;                 // 14 float4 per 56-wide row
            int col = (i4 - r * 14) * 4;
            float* d = &sx[(r + 6) * PW + col + 6];   // word-even -> 8B aligned
            ((float2*)d)[0] = make_float2(stage[k].x, stage[k].y);
            ((float2*)d)[1] = make_float2(stage[k].z, stage[k].w);
        }
    }
    __syncthreads();

    // --- compute: lane (xg,yg) -> out rows [7yg..7yg+6], cols [8xg..8xg+7] ---
    const int xg = tid & 7;
    const int yg = tid >> 3;
    const int xgc = (xg < 7) ? xg : 3;       // idle lane: same-address broadcast with xg=3
    const int Yb = yg * 7;
    const float* __restrict__ sbase = &sx[Yb * PW + 8 * xgc];

    float acc[7][8];
    #pragma unroll
    for (int r = 0; r < 7; r++)
        #pragma unroll
        for (int j = 0; j < 8; j++) acc[r][j] = 0.f;

    // ===== group A: ky 0..6 (5 rows SGPR + 2 rows VGPR), rows i = 0..12 =====
    {
        float wS[5][13];   // -> SGPR via readfirstlane
        float wV[2][13];   // -> VGPR
        #pragma unroll
        for (int dy = 0; dy < 5; dy++) {
            const float* wr = &sw[dy * 16];
            #pragma unroll
            for (int q = 0; q < 3; q++) {
                float4 t = ((const float4*)wr)[q];
                wS[dy][4*q+0] = rfl(t.x); wS[dy][4*q+1] = rfl(t.y);
                wS[dy][4*q+2] = rfl(t.z); wS[dy][4*q+3] = rfl(t.w);
            }
            wS[dy][12] = rfl(wr[12]);
        }
        #pragma unroll
        for (int dy = 0; dy < 2; dy++) {
            const float* wr = &sw[(5 + dy) * 16];
            #pragma unroll
            for (int q = 0; q < 3; q++) {
                float4 t = ((const float4*)wr)[q];
                wV[dy][4*q+0] = t.x; wV[dy][4*q+1] = t.y;
                wV[dy][4*q+2] = t.z; wV[dy][4*q+3] = t.w;
            }
            wV[dy][12] = wr[12];
        }
        #pragma unroll
        for (int i = 0; i < 13; i++) {
            float4 win4[5];
            #pragma unroll
            for (int q = 0; q < 5; q++)
                win4[q] = *(const float4*)(sbase + i * PW + 4 * q);
            const float* win = (const float*)win4;
            #pragma unroll
            for (int dy = 0; dy < 5; dy++) {          // ky = dy
                const int r = i - dy;
                if (r >= 0 && r < 7) {
                    #pragma unroll
                    for (int kx = 0; kx < 13; kx++) {
                        const float wv = wS[dy][kx];
                        #pragma unroll
                        for (int j = 0; j < 8; j++)
                            acc[r][j] = fmaf(wv, win[kx + j], acc[r][j]);
                    }
                }
            }
            #pragma unroll
            for (int dy = 5; dy < 7; dy++) {          // ky = dy
                const int r = i - dy;
                if (r >= 0 && r < 7) {
                    #pragma unroll
                    for (int kx = 0; kx < 13; kx++) {
                        const float wv = wV[dy - 5][kx];
                        #pragma unroll
                        for (int j = 0; j < 8; j++)
                            acc[r][j] = fmaf(wv, win[kx + j], acc[r][j]);
                    }
                }
            }
        }
    }

    // ===== group B: ky 7..12 (5 rows SGPR + 1 row VGPR), rows i = 7..18 =====
    {
        float wS[5][13];
        float wV[1][13];
        #pragma unroll
        for (int dy = 0; dy < 5; dy++) {
            const float* wr = &sw[(7 + dy) * 16];
            #pragma unroll
            for (int q = 0; q < 3; q++) {
                float4 t = ((const float4*)wr)[q];
                wS[dy][4*q+0] = rfl(t.x); wS[dy][4*q+1] = rfl(t.y);
                wS[dy][4*q+2] = rfl(t.z); wS[dy][4*q+3] = rfl(t.w);
            }
            wS[dy][12] = rfl(wr[12]);
        }
        {
            const float* wr = &sw[12 * 16];
            #pragma unroll
            for (int q = 0; q < 3; q++) {
                float4 t = ((const float4*)wr)[q];
                wV[0][4*q+0] = t.x; wV[0][4*q+1] = t.y;
                wV[0][4*q+2] = t.z; wV[0][4*q+3] = t.w;
            }
            wV[0][12] = wr[12];
        }
        #pragma unroll
        for (int i = 7; i < 19; i++) {
            float4 win4[5];
            #pragma unroll
            for (int q = 0; q < 5; q++)
                win4[q] = *(const float4*)(sbase + i * PW + 4 * q);
            const float* win = (const float*)win4;
            #pragma unroll
            for (int dy = 0; dy < 5; dy++) {          // ky = 7+dy
                const int r = i - 7 - dy;
                if (r >= 0 && r < 7) {
                    #pragma unroll
                    for (int kx = 0; kx < 13; kx++) {
                        const float wv = wS[dy][kx];
                        #pragma unroll
                        for (int j = 0; j < 8; j++)
                            acc[r][j] = fmaf(wv, win[kx + j], acc[r][j]);
                    }
                }
            }
            {                                          // ky = 12
                const int r = i - 12;
                if (r >= 0 && r < 7) {
                    #pragma unroll
                    for (int kx = 0; kx < 13; kx++) {
                        const float wv = wV[0][kx];
                        #pragma unroll
                        for (int j = 0; j < 8; j++)
                            acc[r][j] = fmaf(wv, win[kx + j], acc[r][j]);
                    }
                }
            }
        }
    }

    // --- epilogue: +bias, 2x float4 stores per row, idle col group masked ---
    if (xg < 7) {
        float* op = out + (size_t)plane * (SP * SP) + Yb * SP + 8 * xg;
        #pragma unroll
        for (int r = 0; r < 7; r++) {
            float4 v0 = make_float4(acc[r][0] + bias, acc[r][1] + bias,
                                    acc[r][2] + bias, acc[r][3] + bias);
            float4 v1 = make_float4(acc[r][4] + bias, acc[r][5] + bias,
                                    acc[r][6] + bias, acc[r][7] + bias);
            *(float4*)(op + r * SP) = v0;
            *(float4*)(op + r * SP + 4) = v1;
        }
    }
}

extern "C" void kernel_launch(void* const* d_in, const int* in_sizes, int n_in,
                              void* d_out, int out_size, void* d_ws, size_t ws_size,
                              hipStream_t stream) {
    const float* x    = (const float*)d_in[0];
    const float* w_lk = (const float*)d_in[1];
    const float* w_b0 = (const float*)d_in[2];
    const float* w_b1 = (const float*)d_in[3];
    const float* w_b2 = (const float*)d_in[4];
    const float* w_b3 = (const float*)d_in[5];
    const float* w_b4 = (const float*)d_in[6];
    const float* w_b5 = (const float*)d_in[7];
    const float* bn_g = (const float*)d_in[8];
    const float* bn_b = (const float*)d_in[9];
    const float* bn_m = (const float*)d_in[10];
    const float* bn_v = (const float*)d_in[11];
    float* out = (float*)d_out;

    drb_conv13_r11<<<dim3(NPLANES), dim3(64), 0, stream>>>(
        x, w_lk, w_b0, w_b1, w_b2, w_b3, w_b4, w_b5,
        bn_g, bn_b, bn_m, bn_v, out);
}

// Round 9
// 244.529 us; speedup vs baseline: 1.1069x; 1.1019x over previous
//
#include <hip/hip_runtime.h>
#include <hip/hip_fp16.h>

// DilatedReparamBlock folded into one 13x13 depthwise conv + bias.
//
// R12: fp16 LDS staging (compute fp32). R11 post-mortem: VGPR>128 halves
// waves/SIMD (228 VGPR -> occupancy 11%, dur 171 vs R7's 126 despite -33%
// reads) => latency hiding dominates the last reads. The untouched lever is
// the LDS cap: fp32 plane 18.5 KB -> 8 blocks/CU. Staging x as fp16:
//  - tile 68 rows x 72 halves (8 left pad, 56 data, 8 right) = 9792 B;
//    + 832 B weights -> ~10.6 KB -> 15 blocks/CU = 3.75 waves/SIMD;
//  - window = 3 ds_read_b128/row (halves [0..23] of lane base, using
//    [2..21]); reads/lane 185 -> 111; row base byte = 144*R + 16*xgc,
//    16B-aligned by construction;
//  - 20 v_cvt_f32_f16 per row (+8% VALU); weights & accum stay fp32;
//    x-quant err ~2e-3 max, well under 0.0156 tol;
//  - compute structure = R7 verbatim: ky-groups-of-4, 4x13 weights in
//    SGPRs via readfirstlane (52 floats, proven fit at VGPR 116).

#define CCH 384
#define SP 56
#define PWH 72             // halves per padded row
#define NPLANES (16*384)

__device__ __forceinline__ float rfl(float v) {
    return __int_as_float(__builtin_amdgcn_readfirstlane(__float_as_int(v)));
}

typedef __attribute__((ext_vector_type(4))) unsigned int u32x4;

__global__ __launch_bounds__(64, 2) void drb_conv13_r12(
    const float* __restrict__ x,
    const float* __restrict__ w_lk, const float* __restrict__ w_b0,
    const float* __restrict__ w_b1, const float* __restrict__ w_b2,
    const float* __restrict__ w_b3, const float* __restrict__ w_b4,
    const float* __restrict__ w_b5,
    const float* __restrict__ gamma, const float* __restrict__ beta,
    const float* __restrict__ mean, const float* __restrict__ var,
    float* __restrict__ out)
{
    __shared__ __align__(16) __half sxh[68 * PWH];   // 9792 B fp16 plane
    __shared__ __align__(16) float sw[13 * 16];      // merged weights, fp32

    const int plane = blockIdx.x;                 // n*384 + c
    const int c = plane % CCH;
    const int tid = threadIdx.x;
    const float* __restrict__ xp = x + (size_t)plane * (SP * SP);

    // --- prefetch plane into registers (HBM latency hides under LDS init) ---
    float4 stage[13];
    #pragma unroll
    for (int k = 0; k < 13; k++) {
        int i4 = tid + 64 * k;
        if (i4 < SP * SP / 4) stage[k] = ((const float4*)xp)[i4];
    }

    // --- BN fold constants (wave-uniform -> scalar loads) ---
    float S[7];
    float bias = 0.f;
    #pragma unroll
    for (int j = 0; j < 7; j++) {
        float inv = gamma[j * CCH + c] * rsqrtf(var[j * CCH + c] + 1e-5f);
        S[j] = inv;
        bias += beta[j * CCH + c] - mean[j * CCH + c] * inv;
    }

    // --- zero whole fp16 tile: 612 b128 stores ---
    {
        u32x4 z = {0u, 0u, 0u, 0u};
        #pragma unroll
        for (int k = 0; k < 10; k++) {
            int i = tid + 64 * k;
            if (i < (68 * PWH) / 8) ((u32x4*)sxh)[i] = z;
        }
    }

    // --- build merged 13x13 weights (208 slots incl. row pad) ---
    #pragma unroll
    for (int k = 0; k < 4; k++) {
        int t = tid + 64 * k;
        if (t < 13 * 16) {
            int ky = t >> 4, kx = t & 15;
            float w = 0.f;
            if (kx < 13) {
                w = S[0] * w_lk[c * 169 + ky * 13 + kx];                   // 13x13 d1
                if (ky >= 4 && ky <= 8 && kx >= 4 && kx <= 8)              // 5x5 d1 @4
                    w += S[1] * w_b0[c * 25 + (ky - 4) * 5 + (kx - 4)];
                if (ky >= 3 && ky <= 9 && kx >= 3 && kx <= 9)              // 7x7 d1 @3
                    w += S[2] * w_b1[c * 49 + (ky - 3) * 7 + (kx - 3)];
                if (!(ky & 1) && !(kx & 1))                                // 7x7 d2
                    w += S[3] * w_b2[c * 49 + (ky >> 1) * 7 + (kx >> 1)];
                if (ky >= 3 && ky <= 9 && (ky - 3) % 3 == 0 &&
                    kx >= 3 && kx <= 9 && (kx - 3) % 3 == 0)               // 3x3 d3
                    w += S[4] * w_b3[c * 9 + ((ky - 3) / 3) * 3 + (kx - 3) / 3];
                if (ky >= 2 && ky <= 10 && (ky - 2) % 4 == 0 &&
                    kx >= 2 && kx <= 10 && (kx - 2) % 4 == 0)              // 3x3 d4
                    w += S[5] * w_b4[c * 9 + ((ky - 2) / 4) * 3 + (kx - 2) / 4];
                if (ky >= 1 && ky <= 11 && (ky - 1) % 5 == 0 &&
                    kx >= 1 && kx <= 11 && (kx - 1) % 5 == 0)              // 3x3 d5
                    w += S[6] * w_b5[c * 9 + ((ky - 1) / 5) * 3 + (kx - 1) / 5];
            }
            sw[t] = w;
        }
    }

    // --- stage plane into LDS as fp16 (rows 6..61, data halves 8..63) ---
    #pragma unroll
    for (int k = 0; k < 13; k++) {
        int i4 = tid + 64 * k;
        if (i4 < SP * SP / 4) {
            float4 v = stage[k];
            int r = i4 / 14;                 // 14 float4 per 56-wide row
            int col = (i4 - r * 14) * 4;
            __half2* d2 = (__half2*)&sxh[(r + 6) * PWH + col + 8];
            d2[0] = __floats2half2_rn(v.x, v.y);
            d2[1] = __floats2half2_rn(v.z, v.w);
        }
    }
    __syncthreads();

    // --- compute: lane (xg,yg) -> out rows [7yg..7yg+6], cols [8xg..8xg+7] ---
    const int xg = tid & 7;
    const int yg = tid >> 3;
    const int xgc = (xg < 7) ? xg : 3;       // idle lane: broadcast with xg=3
    const int Yb = yg * 7;
    // lane window base: data col 8xgc-6 lives at half idx 8xgc+2 of this base
    const __half* __restrict__ sbaseh = &sxh[Yb * PWH + 8 * xgc];

    float acc[7][8];
    #pragma unroll
    for (int r = 0; r < 7; r++)
        #pragma unroll
        for (int j = 0; j < 8; j++) acc[r][j] = 0.f;

    // row load: 3 b128 (halves 0..23), convert halves 2..21 -> win[0..19]
#define LOADROW(WF, ROWP)                                                   \
    {                                                                       \
        const u32x4* cp_ = (const u32x4*)(ROWP);                            \
        u32x4 c0_ = cp_[0];                                                 \
        const __half2* p0_ = (const __half2*)&c0_;                          \
        float2 f_;                                                          \
        f_ = __half22float2(p0_[1]); WF[0] = f_.x; WF[1] = f_.y;            \
        f_ = __half22float2(p0_[2]); WF[2] = f_.x; WF[3] = f_.y;            \
        f_ = __half22float2(p0_[3]); WF[4] = f_.x; WF[5] = f_.y;            \
        u32x4 c1_ = cp_[1];                                                 \
        const __half2* p1_ = (const __half2*)&c1_;                          \
        f_ = __half22float2(p1_[0]); WF[6] = f_.x; WF[7] = f_.y;            \
        f_ = __half22float2(p1_[1]); WF[8] = f_.x; WF[9] = f_.y;            \
        f_ = __half22float2(p1_[2]); WF[10] = f_.x; WF[11] = f_.y;          \
        f_ = __half22float2(p1_[3]); WF[12] = f_.x; WF[13] = f_.y;          \
        u32x4 c2_ = cp_[2];                                                 \
        const __half2* p2_ = (const __half2*)&c2_;                          \
        f_ = __half22float2(p2_[0]); WF[14] = f_.x; WF[15] = f_.y;          \
        f_ = __half22float2(p2_[1]); WF[16] = f_.x; WF[17] = f_.y;          \
        f_ = __half22float2(p2_[2]); WF[18] = f_.x; WF[19] = f_.y;          \
    }

    // ky groups of 4: input rows k0..k0+9 each read ONCE, serve 4 weight rows.
    #pragma unroll 1
    for (int k0 = 0; k0 < 12; k0 += 4) {
        float w[4][13];   // wave-uniform -> SGPRs via readfirstlane
        #pragma unroll
        for (int dy = 0; dy < 4; dy++) {
            const float* wr = &sw[(k0 + dy) * 16];
            #pragma unroll
            for (int q = 0; q < 3; q++) {
                float4 t = ((const float4*)wr)[q];
                w[dy][4*q+0] = rfl(t.x); w[dy][4*q+1] = rfl(t.y);
                w[dy][4*q+2] = rfl(t.z); w[dy][4*q+3] = rfl(t.w);
            }
            w[dy][12] = rfl(wr[12]);
        }
        #pragma unroll
        for (int i = 0; i < 10; i++) {
            float win[20];
            LOADROW(win, sbaseh + (k0 + i) * PWH);
            #pragma unroll
            for (int dy = 0; dy < 4; dy++) {
                const int r = i - dy;
                if (r >= 0 && r < 7) {
                    #pragma unroll
                    for (int kx = 0; kx < 13; kx++) {
                        const float wv = w[dy][kx];
                        #pragma unroll
                        for (int j = 0; j < 8; j++)
                            acc[r][j] = fmaf(wv, win[kx + j], acc[r][j]);
                    }
                }
            }
        }
    }
    // tail ky = 12 (rows Yb+12..Yb+18)
    {
        float w12[13];
        const float* wr = &sw[12 * 16];
        #pragma unroll
        for (int q = 0; q < 3; q++) {
            float4 t = ((const float4*)wr)[q];
            w12[4*q+0] = rfl(t.x); w12[4*q+1] = rfl(t.y);
            w12[4*q+2] = rfl(t.z); w12[4*q+3] = rfl(t.w);
        }
        w12[12] = rfl(wr[12]);
        #pragma unroll
        for (int i = 0; i < 7; i++) {
            float win[20];
            LOADROW(win, sbaseh + (12 + i) * PWH);
            #pragma unroll
            for (int kx = 0; kx < 13; kx++) {
                const float wv = w12[kx];
                #pragma unroll
                for (int j = 0; j < 8; j++)
                    acc[i][j] = fmaf(wv, win[kx + j], acc[i][j]);
            }
        }
    }
#undef LOADROW

    // --- epilogue: +bias, 2x float4 stores per row, idle col group masked ---
    if (xg < 7) {
        float* op = out + (size_t)plane * (SP * SP) + Yb * SP + 8 * xg;
        #pragma unroll
        for (int r = 0; r < 7; r++) {
            float4 v0 = make_float4(acc[r][0] + bias, acc[r][1] + bias,
                                    acc[r][2] + bias, acc[r][3] + bias);
            float4 v1 = make_float4(acc[r][4] + bias, acc[r][5] + bias,
                                    acc[r][6] + bias, acc[r][7] + bias);
            *(float4*)(op + r * SP) = v0;
            *(float4*)(op + r * SP + 4) = v1;
        }
    }
}

extern "C" void kernel_launch(void* const* d_in, const int* in_sizes, int n_in,
                              void* d_out, int out_size, void* d_ws, size_t ws_size,
                              hipStream_t stream) {
    const float* x    = (const float*)d_in[0];
    const float* w_lk = (const float*)d_in[1];
    const float* w_b0 = (const float*)d_in[2];
    const float* w_b1 = (const float*)d_in[3];
    const float* w_b2 = (const float*)d_in[4];
    const float* w_b3 = (const float*)d_in[5];
    const float* w_b4 = (const float*)d_in[6];
    const float* w_b5 = (const float*)d_in[7];
    const float* bn_g = (const float*)d_in[8];
    const float* bn_b = (const float*)d_in[9];
    const float* bn_m = (const float*)d_in[10];
    const float* bn_v = (const float*)d_in[11];
    float* out = (float*)d_out;

    drb_conv13_r12<<<dim3(NPLANES), dim3(64), 0, stream>>>(
        x, w_lk, w_b0, w_b1, w_b2, w_b3, w_b4, w_b5,
        bn_g, bn_b, bn_m, bn_v, out);
}

// Round 10
// 219.937 us; speedup vs baseline: 1.2306x; 1.1118x over previous
//
#include <hip/hip_runtime.h>
#include <hip/hip_fp16.h>

// DilatedReparamBlock folded into one 13x13 depthwise conv + bias.
//
// R13: occupancy via multi-wave workgroups. Cross-round evidence (R4 38.5%
// @128thr; R7/R12 ~20% @64thr regardless of LDS 19.4/10.7 KB): the CU holds
// ~8 WORKGROUPS regardless of LDS headroom, so single-wave blocks cap at
// ~8 waves/CU. Fix: 128-thread block = 2 waves = 2 INDEPENDENT planes
// (wave w owns plane 2*blockIdx+w, its own fp16 tile + weight table).
// fp16 staging (R12) is the enabler: 2x10.6 KB = 21.2 KB/block -> 7
// blocks/CU x 2 waves = ~14 waves/CU, while LDS-pipe demand (halved reads,
// conflicts 5.8e6) stays far below the VALU floor. Compute = R12 verbatim.

#define CCH 384
#define SP 56
#define PWH 72             // halves per padded row (16B-aligned lane bases)
#define NPLANES (16*384)

__device__ __forceinline__ float rfl(float v) {
    return __int_as_float(__builtin_amdgcn_readfirstlane(__float_as_int(v)));
}

typedef __attribute__((ext_vector_type(4))) unsigned int u32x4;

__global__ __launch_bounds__(128) void drb_conv13_r13(
    const float* __restrict__ x,
    const float* __restrict__ w_lk, const float* __restrict__ w_b0,
    const float* __restrict__ w_b1, const float* __restrict__ w_b2,
    const float* __restrict__ w_b3, const float* __restrict__ w_b4,
    const float* __restrict__ w_b5,
    const float* __restrict__ gamma, const float* __restrict__ beta,
    const float* __restrict__ mean, const float* __restrict__ var,
    float* __restrict__ out)
{
    __shared__ __align__(16) __half sxh2[2][68 * PWH];   // 2 x 9792 B fp16 planes
    __shared__ __align__(16) float sw2[2][13 * 16];      // 2 x 832 B weights

    const int wid  = threadIdx.x >> 6;            // wave id: 0,1
    const int lane = threadIdx.x & 63;
    const int plane = blockIdx.x * 2 + wid;       // n*384 + c
    const int c = plane % CCH;
    const float* __restrict__ xp = x + (size_t)plane * (SP * SP);
    __half* __restrict__ sxh = sxh2[wid];
    float* __restrict__ sw = sw2[wid];

    // --- prefetch plane into registers (HBM latency hides under LDS init) ---
    float4 stage[13];
    #pragma unroll
    for (int k = 0; k < 13; k++) {
        int i4 = lane + 64 * k;
        if (i4 < SP * SP / 4) stage[k] = ((const float4*)xp)[i4];
    }

    // --- BN fold constants (wave-uniform -> scalar loads) ---
    float S[7];
    float bias = 0.f;
    #pragma unroll
    for (int j = 0; j < 7; j++) {
        float inv = gamma[j * CCH + c] * rsqrtf(var[j * CCH + c] + 1e-5f);
        S[j] = inv;
        bias += beta[j * CCH + c] - mean[j * CCH + c] * inv;
    }

    // --- zero this wave's fp16 tile: 612 b128 stores ---
    {
        u32x4 z = {0u, 0u, 0u, 0u};
        #pragma unroll
        for (int k = 0; k < 10; k++) {
            int i = lane + 64 * k;
            if (i < (68 * PWH) / 8) ((u32x4*)sxh)[i] = z;
        }
    }

    // --- build merged 13x13 weights (208 slots incl. row pad) ---
    #pragma unroll
    for (int k = 0; k < 4; k++) {
        int t = lane + 64 * k;
        if (t < 13 * 16) {
            int ky = t >> 4, kx = t & 15;
            float w = 0.f;
            if (kx < 13) {
                w = S[0] * w_lk[c * 169 + ky * 13 + kx];                   // 13x13 d1
                if (ky >= 4 && ky <= 8 && kx >= 4 && kx <= 8)              // 5x5 d1 @4
                    w += S[1] * w_b0[c * 25 + (ky - 4) * 5 + (kx - 4)];
                if (ky >= 3 && ky <= 9 && kx >= 3 && kx <= 9)              // 7x7 d1 @3
                    w += S[2] * w_b1[c * 49 + (ky - 3) * 7 + (kx - 3)];
                if (!(ky & 1) && !(kx & 1))                                // 7x7 d2
                    w += S[3] * w_b2[c * 49 + (ky >> 1) * 7 + (kx >> 1)];
                if (ky >= 3 && ky <= 9 && (ky - 3) % 3 == 0 &&
                    kx >= 3 && kx <= 9 && (kx - 3) % 3 == 0)               // 3x3 d3
                    w += S[4] * w_b3[c * 9 + ((ky - 3) / 3) * 3 + (kx - 3) / 3];
                if (ky >= 2 && ky <= 10 && (ky - 2) % 4 == 0 &&
                    kx >= 2 && kx <= 10 && (kx - 2) % 4 == 0)              // 3x3 d4
                    w += S[5] * w_b4[c * 9 + ((ky - 2) / 4) * 3 + (kx - 2) / 4];
                if (ky >= 1 && ky <= 11 && (ky - 1) % 5 == 0 &&
                    kx >= 1 && kx <= 11 && (kx - 1) % 5 == 0)              // 3x3 d5
                    w += S[6] * w_b5[c * 9 + ((ky - 1) / 5) * 3 + (kx - 1) / 5];
            }
            sw[t] = w;
        }
    }

    // --- stage plane into LDS as fp16 (rows 6..61, data halves 8..63) ---
    #pragma unroll
    for (int k = 0; k < 13; k++) {
        int i4 = lane + 64 * k;
        if (i4 < SP * SP / 4) {
            float4 v = stage[k];
            int r = i4 / 14;                 // 14 float4 per 56-wide row
            int col = (i4 - r * 14) * 4;
            __half2* d2 = (__half2*)&sxh[(r + 6) * PWH + col + 8];
            d2[0] = __floats2half2_rn(v.x, v.y);
            d2[1] = __floats2half2_rn(v.z, v.w);
        }
    }
    __syncthreads();   // symmetric waves: negligible skew; also fences LDS

    // --- compute: lane (xg,yg) -> out rows [7yg..7yg+6], cols [8xg..8xg+7] ---
    const int xg = lane & 7;
    const int yg = lane >> 3;
    const int xgc = (xg < 7) ? xg : 3;       // idle lane: broadcast with xg=3
    const int Yb = yg * 7;
    const __half* __restrict__ sbaseh = &sxh[Yb * PWH + 8 * xgc];

    float acc[7][8];
    #pragma unroll
    for (int r = 0; r < 7; r++)
        #pragma unroll
        for (int j = 0; j < 8; j++) acc[r][j] = 0.f;

    // row load: 3 b128 (halves 0..23), convert halves 2..21 -> win[0..19]
#define LOADROW(WF, ROWP)                                                   \
    {                                                                       \
        const u32x4* cp_ = (const u32x4*)(ROWP);                            \
        u32x4 c0_ = cp_[0];                                                 \
        const __half2* p0_ = (const __half2*)&c0_;                          \
        float2 f_;                                                          \
        f_ = __half22float2(p0_[1]); WF[0] = f_.x; WF[1] = f_.y;            \
        f_ = __half22float2(p0_[2]); WF[2] = f_.x; WF[3] = f_.y;            \
        f_ = __half22float2(p0_[3]); WF[4] = f_.x; WF[5] = f_.y;            \
        u32x4 c1_ = cp_[1];                                                 \
        const __half2* p1_ = (const __half2*)&c1_;                          \
        f_ = __half22float2(p1_[0]); WF[6] = f_.x; WF[7] = f_.y;            \
        f_ = __half22float2(p1_[1]); WF[8] = f_.x; WF[9] = f_.y;            \
        f_ = __half22float2(p1_[2]); WF[10] = f_.x; WF[11] = f_.y;          \
        f_ = __half22float2(p1_[3]); WF[12] = f_.x; WF[13] = f_.y;          \
        u32x4 c2_ = cp_[2];                                                 \
        const __half2* p2_ = (const __half2*)&c2_;                          \
        f_ = __half22float2(p2_[0]); WF[14] = f_.x; WF[15] = f_.y;          \
        f_ = __half22float2(p2_[1]); WF[16] = f_.x; WF[17] = f_.y;          \
        f_ = __half22float2(p2_[2]); WF[18] = f_.x; WF[19] = f_.y;          \
    }

    // ky groups of 4: input rows k0..k0+9 each read ONCE, serve 4 weight rows.
    #pragma unroll 1
    for (int k0 = 0; k0 < 12; k0 += 4) {
        float w[4][13];   // wave-uniform -> SGPRs via readfirstlane
        #pragma unroll
        for (int dy = 0; dy < 4; dy++) {
            const float* wr = &sw[(k0 + dy) * 16];
            #pragma unroll
            for (int q = 0; q < 3; q++) {
                float4 t = ((const float4*)wr)[q];
                w[dy][4*q+0] = rfl(t.x); w[dy][4*q+1] = rfl(t.y);
                w[dy][4*q+2] = rfl(t.z); w[dy][4*q+3] = rfl(t.w);
            }
            w[dy][12] = rfl(wr[12]);
        }
        #pragma unroll
        for (int i = 0; i < 10; i++) {
            float win[20];
            LOADROW(win, sbaseh + (k0 + i) * PWH);
            #pragma unroll
            for (int dy = 0; dy < 4; dy++) {
                const int r = i - dy;
                if (r >= 0 && r < 7) {
                    #pragma unroll
                    for (int kx = 0; kx < 13; kx++) {
                        const float wv = w[dy][kx];
                        #pragma unroll
                        for (int j = 0; j < 8; j++)
                            acc[r][j] = fmaf(wv, win[kx + j], acc[r][j]);
                    }
                }
            }
        }
    }
    // tail ky = 12 (rows Yb+12..Yb+18)
    {
        float w12[13];
        const float* wr = &sw[12 * 16];
        #pragma unroll
        for (int q = 0; q < 3; q++) {
            float4 t = ((const float4*)wr)[q];
            w12[4*q+0] = rfl(t.x); w12[4*q+1] = rfl(t.y);
            w12[4*q+2] = rfl(t.z); w12[4*q+3] = rfl(t.w);
        }
        w12[12] = rfl(wr[12]);
        #pragma unroll
        for (int i = 0; i < 7; i++) {
            float win[20];
            LOADROW(win, sbaseh + (12 + i) * PWH);
            #pragma unroll
            for (int kx = 0; kx < 13; kx++) {
                const float wv = w12[kx];
                #pragma unroll
                for (int j = 0; j < 8; j++)
                    acc[i][j] = fmaf(wv, win[kx + j], acc[i][j]);
            }
        }
    }
#undef LOADROW

    // --- epilogue: +bias, 2x float4 stores per row, idle col group masked ---
    if (xg < 7) {
        float* op = out + (size_t)plane * (SP * SP) + Yb * SP + 8 * xg;
        #pragma unroll
        for (int r = 0; r < 7; r++) {
            float4 v0 = make_float4(acc[r][0] + bias, acc[r][1] + bias,
                                    acc[r][2] + bias, acc[r][3] + bias);
            float4 v1 = make_float4(acc[r][4] + bias, acc[r][5] + bias,
                                    acc[r][6] + bias, acc[r][7] + bias);
            *(float4*)(op + r * SP) = v0;
            *(float4*)(op + r * SP + 4) = v1;
        }
    }
}

extern "C" void kernel_launch(void* const* d_in, const int* in_sizes, int n_in,
                              void* d_out, int out_size, void* d_ws, size_t ws_size,
                              hipStream_t stream) {
    const float* x    = (const float*)d_in[0];
    const float* w_lk = (const float*)d_in[1];
    const float* w_b0 = (const float*)d_in[2];
    const float* w_b1 = (const float*)d_in[3];
    const float* w_b2 = (const float*)d_in[4];
    const float* w_b3 = (const float*)d_in[5];
    const float* w_b4 = (const float*)d_in[6];
    const float* w_b5 = (const float*)d_in[7];
    const float* bn_g = (const float*)d_in[8];
    const float* bn_b = (const float*)d_in[9];
    const float* bn_m = (const float*)d_in[10];
    const float* bn_v = (const float*)d_in[11];
    float* out = (float*)d_out;

    drb_conv13_r13<<<dim3(NPLANES / 2), dim3(128), 0, stream>>>(
        x, w_lk, w_b0, w_b1, w_b2, w_b3, w_b4, w_b5,
        bn_g, bn_b, bn_m, bn_v, out);
}